// Round 1
// baseline (616.899 us; speedup 1.0000x reference)
//
#include <hip/hip_runtime.h>
#include <stdint.h>

typedef uint32_t u32;
typedef uint64_t u64;

#define NB 8
#define NPER 4000
#define NROWS (NB * NPER)
#define NC 91
#define NCLS 90
#define CAPMAX 76800   // hard bound: <=19 classes/proposal can have softmax > 0.05
#define LDSK 15104
#define NDET 100

// ---------------------------------------------------------------- decode ----
__device__ __forceinline__ float4 decode_clip(float4 rel, float w, float h,
                                              float cx, float cy, float W, float H) {
  const float XCLIP = 4.135166556742356f;  // log(1000/16)
  float dx = rel.x / 10.0f;
  float dy = rel.y / 10.0f;
  float dw = fminf(rel.z / 5.0f, XCLIP);
  float dh = fminf(rel.w / 5.0f, XCLIP);
  float qcx = dx * w + cx;
  float qcy = dy * h + cy;
  float qw = expf(dw) * w;
  float qh = expf(dh) * h;
  float x1 = qcx - 0.5f * qw, y1 = qcy - 0.5f * qh;
  float x2 = qcx + 0.5f * qw, y2 = qcy + 0.5f * qh;
  x1 = fminf(fmaxf(x1, 0.0f), W);
  x2 = fminf(fmaxf(x2, 0.0f), W);
  y1 = fminf(fmaxf(y1, 0.0f), H);
  y2 = fminf(fmaxf(y2, 0.0f), H);
  return make_float4(x1, y1, x2, y2);
}

// One wave (64 lanes) per proposal row. Lane handles class cA=lane and
// cB=64+lane (lane<27). Softmax over all 91 classes (incl. background).
__device__ __forceinline__ void row_candidates(const float* __restrict__ logits,
    const float* __restrict__ boxreg, const float* __restrict__ props,
    int r, int lane, float W, float H,
    int& cA, bool& vA, float& sA, float4& bA,
    int& cB, bool& vB, float& sB, float4& bB) {
  const float* lrow = logits + (size_t)r * NC;
  float xA = lrow[lane];
  float xB = (lane < NC - 64) ? lrow[64 + lane] : -3.0e38f;
  float mx = fmaxf(xA, xB);
  for (int o = 32; o; o >>= 1) mx = fmaxf(mx, __shfl_xor(mx, o));
  float eA = expf(xA - mx);
  float eB = (lane < NC - 64) ? expf(xB - mx) : 0.0f;
  float sm = eA + eB;
  for (int o = 32; o; o >>= 1) sm += __shfl_xor(sm, o);
  sA = eA / sm;
  sB = eB / sm;
  cA = lane;
  cB = 64 + lane;
  const float4 p = reinterpret_cast<const float4*>(props)[r];
  float w = p.z - p.x, h = p.w - p.y;
  float cx = p.x + 0.5f * w, cy = p.y + 0.5f * h;
  vA = (cA >= 1) && (sA > 0.05f);
  vB = (cB < NC) && (sB > 0.05f);
  bA = make_float4(0.f, 0.f, 0.f, 0.f);
  bB = bA;
  // box_regression row: 364 floats = 91 float4s, 16B-aligned (r*1456)
  const float4* relrow = reinterpret_cast<const float4*>(boxreg) + (size_t)r * NC;
  if (vA) {
    bA = decode_clip(relrow[cA], w, h, cx, cy, W, H);
    vA = ((bA.z - bA.x) >= 0.01f) && ((bA.w - bA.y) >= 0.01f);
  }
  if (vB) {
    bB = decode_clip(relrow[cB], w, h, cx, cy, W, H);
    vB = ((bB.z - bB.x) >= 0.01f) && ((bB.w - bB.y) >= 0.01f);
  }
}

// ---------------------------------------------------------------- kernels ---
__global__ __launch_bounds__(1024) void k_zero(u32* ccount) {
  int t = threadIdx.x;
  if (t < NB * NCLS) ccount[t] = 0u;
}

__global__ __launch_bounds__(256) void k_count(const float* __restrict__ logits,
    const float* __restrict__ boxreg, const float* __restrict__ props,
    const int* __restrict__ dh, const int* __restrict__ dw, u32* ccount) {
  int gt = blockIdx.x * 256 + threadIdx.x;
  int r = gt >> 6, lane = gt & 63;
  if (r >= NROWS) return;
  float H = (float)dh[0], W = (float)dw[0];
  int cA, cB; bool vA, vB; float sA, sB; float4 bA, bB;
  row_candidates(logits, boxreg, props, r, lane, W, H, cA, vA, sA, bA, cB, vB, sB, bB);
  int b = r / NPER;
  if (vA) atomicAdd(ccount + b * NCLS + (cA - 1), 1u);
  if (vB) atomicAdd(ccount + b * NCLS + (cB - 1), 1u);
}

// segmented (per-image) exclusive scan over the 8x90 class counts
__global__ __launch_bounds__(1024) void k_scan(const u32* __restrict__ ccount, u32* cbase) {
  __shared__ u32 s[NB * NCLS];
  int t = threadIdx.x;
  u32 own = 0;
  if (t < NB * NCLS) { own = ccount[t]; s[t] = own; }
  __syncthreads();
  int i = t % NCLS;
  for (int off = 1; off < NCLS; off <<= 1) {
    u32 add = 0;
    if (t < NB * NCLS && i >= off) add = s[t - off];
    __syncthreads();
    if (t < NB * NCLS) s[t] += add;
    __syncthreads();
  }
  if (t < NB * NCLS) cbase[t] = s[t] - own;  // exclusive; k_place restores inclusive
}

__global__ __launch_bounds__(256) void k_place(const float* __restrict__ logits,
    const float* __restrict__ boxreg, const float* __restrict__ props,
    const int* __restrict__ dh, const int* __restrict__ dw, u32* cbase,
    float4* box_all, u32* sc_all, u32* lab_all, int CAP) {
  int gt = blockIdx.x * 256 + threadIdx.x;
  int r = gt >> 6, lane = gt & 63;
  if (r >= NROWS) return;
  float H = (float)dh[0], W = (float)dw[0];
  int cA, cB; bool vA, vB; float sA, sB; float4 bA, bB;
  row_candidates(logits, boxreg, props, r, lane, W, H, cA, vA, sA, bA, cB, vB, sB, bB);
  int b = r / NPER;
  size_t base = (size_t)b * CAP;
  if (vA) {
    u32 pos = atomicAdd(cbase + b * NCLS + (cA - 1), 1u);
    if (pos < (u32)CAP) {
      box_all[base + pos] = bA;
      sc_all[base + pos] = __float_as_uint(sA);
      lab_all[base + pos] = (u32)cA;
    }
  }
  if (vB) {
    u32 pos = atomicAdd(cbase + b * NCLS + (cB - 1), 1u);
    if (pos < (u32)CAP) {
      box_all[base + pos] = bB;
      sc_all[base + pos] = __float_as_uint(sB);
      lab_all[base + pos] = (u32)cB;
    }
  }
}

// One block per image. Scores (u32 bit patterns, 0 = dead) in LDS; 100 steps
// of argmax + intra-class-segment suppression. Outputs staged in LDS.
__global__ __launch_bounds__(1024) void k_nms(const u32* __restrict__ cbase_post,
    const float4* __restrict__ box_all, u32* sc_all, const u32* __restrict__ lab_all,
    const int* __restrict__ dh, const int* __restrict__ dw, float* out, int CAP) {
  __shared__ u32 s_sc[LDSK];
  __shared__ u64 s_red[16];
  __shared__ float s_out[NDET][8];
  __shared__ float4 s_ob;
  __shared__ float s_area;
  __shared__ u32 s_sel[4];  // 0: done, 1: seg start, 2: seg end, 3: label

  int b = blockIdx.x;
  int tid = threadIdx.x;
  float H = (float)dh[0], W = (float)dw[0];
  float off_unit = fmaxf(H, W) + 1.0f;

  const u32* post = cbase_post + b * NCLS;  // inclusive class ends after k_place
  int K = (int)min(post[NCLS - 1], (u32)CAP);
  u32* sg = sc_all + (size_t)b * CAP;
  const float4* bg = box_all + (size_t)b * CAP;
  const u32* lg = lab_all + (size_t)b * CAP;
  int KL = (K < LDSK) ? K : LDSK;

  for (int j = tid; j < LDSK; j += 1024) s_sc[j] = (j < KL) ? sg[j] : 0u;
  for (int j = tid; j < NDET * 8; j += 1024) ((float*)s_out)[j] = 0.0f;
  if (tid == 0) s_sel[0] = 0;
  __syncthreads();

  for (int t = 0; t < NDET; ++t) {
    // ---- argmax over (score bits, tie -> smaller j) ----
    u64 best = 0;
    for (int j = tid; j < KL; j += 1024) {
      u64 k = ((u64)s_sc[j] << 32) | (u64)(0xFFFFFFFFu - (u32)j);
      best = (k > best) ? k : best;
    }
    for (int j = LDSK + tid; j < K; j += 1024) {
      u64 k = ((u64)sg[j] << 32) | (u64)(0xFFFFFFFFu - (u32)j);
      best = (k > best) ? k : best;
    }
    for (int o = 32; o; o >>= 1) {
      u64 v = __shfl_xor(best, o);
      best = (v > best) ? v : best;
    }
    if ((tid & 63) == 0) s_red[tid >> 6] = best;
    __syncthreads();
    if (tid == 0) {
      u64 bb = 0;
      for (int w = 0; w < 16; ++w) bb = (s_red[w] > bb) ? s_red[w] : bb;
      u32 scb = (u32)(bb >> 32);
      if (scb == 0) {
        s_sel[0] = 1;  // pool empty: remaining outputs stay zero
      } else {
        int j = (int)(0xFFFFFFFFu - (u32)(bb & 0xFFFFFFFFu));
        float4 bx = bg[j];
        u32 lab = lg[j];
        float loff = (float)lab * off_unit;
        float4 ob = make_float4(bx.x + loff, bx.y + loff, bx.z + loff, bx.w + loff);
        float* o7 = s_out[t];
        o7[0] = bx.x; o7[1] = bx.y; o7[2] = bx.z; o7[3] = bx.w;
        o7[4] = __uint_as_float(scb);
        o7[5] = (float)lab;
        o7[6] = 1.0f;
        s_ob = ob;
        s_area = (ob.z - ob.x) * (ob.w - ob.y);
        int ci = (int)lab - 1;
        u32 s0 = (ci == 0) ? 0u : post[ci - 1];
        u32 s1 = post[ci];
        s_sel[1] = (s0 < (u32)CAP) ? s0 : (u32)CAP;
        s_sel[2] = (s1 < (u32)CAP) ? s1 : (u32)CAP;
        s_sel[3] = lab;
      }
    }
    __syncthreads();
    if (s_sel[0]) break;  // uniform
    // ---- suppression: same-class segment only (cross-class IoU == 0) ----
    int seg0 = (int)s_sel[1], seg1 = (int)s_sel[2];
    float loff = (float)s_sel[3] * off_unit;
    float4 A = s_ob;
    float aA = s_area;
    for (int j = seg0 + tid; j < seg1; j += 1024) {
      u32 sc = (j < LDSK) ? s_sc[j] : sg[j];
      if (!sc) continue;
      float4 bj = bg[j];
      float4 Bb = make_float4(bj.x + loff, bj.y + loff, bj.z + loff, bj.w + loff);
      float ix1 = fmaxf(A.x, Bb.x), iy1 = fmaxf(A.y, Bb.y);
      float ix2 = fminf(A.z, Bb.z), iy2 = fminf(A.w, Bb.w);
      float inter = fmaxf(ix2 - ix1, 0.0f) * fmaxf(iy2 - iy1, 0.0f);
      float aB = (Bb.z - Bb.x) * (Bb.w - Bb.y);
      float iou = inter / fmaxf(aA + aB - inter, 1e-9f);
      if (iou > 0.5f) {  // self (IoU=1) suppressed here too -> removed from pool
        if (j < LDSK) s_sc[j] = 0u; else sg[j] = 0u;
      }
    }
    __syncthreads();
  }
  __syncthreads();
  // ---- write outputs: boxes[3200] | scores[800] | labels[800] | keep[800] ----
  if (tid < NDET) {
    const float* o7 = s_out[tid];
    float* ob_out = out + ((size_t)b * NDET + tid) * 4;
    ob_out[0] = o7[0]; ob_out[1] = o7[1]; ob_out[2] = o7[2]; ob_out[3] = o7[3];
    out[NB * NDET * 4 + b * NDET + tid] = o7[4];
    out[NB * NDET * 5 + b * NDET + tid] = o7[5];
    out[NB * NDET * 6 + b * NDET + tid] = o7[6];
  }
}

// ---------------------------------------------------------------- launch ----
extern "C" void kernel_launch(void* const* d_in, const int* in_sizes, int n_in,
                              void* d_out, int out_size, void* d_ws, size_t ws_size,
                              hipStream_t stream) {
  const float* logits = (const float*)d_in[0];
  const float* boxreg = (const float*)d_in[1];
  const float* props  = (const float*)d_in[2];
  const int* dh = (const int*)d_in[3];
  const int* dw = (const int*)d_in[4];
  float* out = (float*)d_out;

  char* ws = (char*)d_ws;
  u32* ccount = (u32*)ws;            // 720 u32
  u32* cbase  = (u32*)(ws + 4096);   // 720 u32
  char* arrs  = ws + 8192;
  size_t avail = (ws_size > 8192) ? (ws_size - 8192) : 0;
  size_t cap = avail / (NB * 24);    // 16B box + 4B score + 4B label per cand
  if (cap > CAPMAX) cap = CAPMAX;
  cap &= ~(size_t)15;
  int CAP = (int)cap;
  float4* box_all = (float4*)arrs;
  u32* sc_all  = (u32*)(box_all + (size_t)NB * CAP);
  u32* lab_all = sc_all + (size_t)NB * CAP;

  k_zero<<<1, 1024, 0, stream>>>(ccount);
  k_count<<<NROWS / 4, 256, 0, stream>>>(logits, boxreg, props, dh, dw, ccount);
  k_scan<<<1, 1024, 0, stream>>>(ccount, cbase);
  k_place<<<NROWS / 4, 256, 0, stream>>>(logits, boxreg, props, dh, dw, cbase,
                                         box_all, sc_all, lab_all, CAP);
  k_nms<<<NB, 1024, 0, stream>>>(cbase, box_all, sc_all, lab_all, dh, dw, out, CAP);
}